// Round 1
// 677.168 us; speedup vs baseline: 1.0199x; 1.0199x over previous
//
#include <hip/hip_runtime.h>
#include <stdint.h>

#define B_N 512
#define E_N 1024
#define ML_N 50
#define V_N 50000
#define V_PAD 50048   // 391 * 128

typedef __bf16 bf16_t;
typedef __bf16 bf16x8 __attribute__((ext_vector_type(8)));
typedef float f32x4 __attribute__((ext_vector_type(4)));

__device__ __forceinline__ uint16_t f2bf(float f) {
    union { float f; uint32_t u; } v; v.f = f;
    return (uint16_t)((v.u + 0x7FFFu + ((v.u >> 16) & 1u)) >> 16);  // RNE
}
__device__ __forceinline__ uint32_t packbf2(float lo, float hi) {
    return (uint32_t)f2bf(lo) | ((uint32_t)f2bf(hi) << 16);
}
__device__ __forceinline__ void load_lds16(const void* g, void* l) {
    __builtin_amdgcn_global_load_lds((const __attribute__((address_space(1))) void*)g,
                                     (__attribute__((address_space(3))) void*)l, 16, 0, 0);
}
__device__ __forceinline__ bf16x8 cvt8(float4 x, float4 y) {
    bf16x8 r;
    r[0] = (bf16_t)x.x; r[1] = (bf16_t)x.y; r[2] = (bf16_t)x.z; r[3] = (bf16_t)x.w;
    r[4] = (bf16_t)y.x; r[5] = (bf16_t)y.y; r[6] = (bf16_t)y.z; r[7] = (bf16_t)y.w;
    return r;
}

// ---------------------------------------------------------------------------
// K0: classify padded_positions dtype: 0 = int32 {0,1}, 1 = float32 {0,1.0f},
// 2 = byte. Reads first 25600 bytes (in-bounds under every interpretation).
__global__ __launch_bounds__(256) void detect_mask_mode(const uint32_t* __restrict__ mp,
                                                        int* __restrict__ mode_out) {
    __shared__ int s_int_ok, s_flt_ok;
    if (threadIdx.x == 0) { s_int_ok = 1; s_flt_ok = 1; }
    __syncthreads();
    int int_ok = 1, flt_ok = 1;
    for (int i = threadIdx.x; i < 6400; i += 256) {
        uint32_t v = mp[i];
        if (!(v == 0u || v == 1u)) int_ok = 0;
        if (!(v == 0u || v == 0x3F800000u)) flt_ok = 0;
    }
    if (!int_ok) atomicAnd(&s_int_ok, 0);
    if (!flt_ok) atomicAnd(&s_flt_ok, 0);
    __syncthreads();
    if (threadIdx.x == 0) *mode_out = s_int_ok ? 0 : (s_flt_ok ? 1 : 2);
}

// ---------------------------------------------------------------------------
// K1 fused: energies + masked softmax + contexts + embed gather.
// One block per batch row, 512 threads. Pass 1 streams enc (HBM); pass 2
// re-reads the same 205 KB slice (L2/LLC-hot). fp32 math identical to the
// previous two-kernel version.
__global__ __launch_bounds__(512) void attn_kernel(
    const float* __restrict__ enc, const float* __restrict__ h0,
    const void* __restrict__ maskp, const int* __restrict__ mode_p,
    const int* __restrict__ ts, const float* __restrict__ emb,
    float* __restrict__ ctx_f, bf16_t* __restrict__ a_lstm)
{
    __shared__ float hs[E_N];
    __shared__ float en[64];
    __shared__ float nrm[64];

    int b = blockIdx.x;
    int tid = threadIdx.x;
    int lane = tid & 63, wv = tid >> 6;   // 8 waves

    if (tid < 256)
        ((float4*)hs)[tid] = ((const float4*)(h0 + (size_t)b * E_N))[tid];
    __syncthreads();

    const float* encb = enc + (size_t)b * ML_N * E_N;

    // pass 1: energies (one row per wave, strided by 8)
    for (int l = wv; l < ML_N; l += 8) {
        const float4* row = (const float4*)(encb + l * E_N);
        float acc = 0.f;
        #pragma unroll
        for (int t = 0; t < 4; t++) {
            float4 e4 = row[lane + 64 * t];
            float4 h4 = ((const float4*)hs)[lane + 64 * t];
            acc += e4.x * h4.x + e4.y * h4.y + e4.z * h4.z + e4.w * h4.w;
        }
        #pragma unroll
        for (int off = 32; off > 0; off >>= 1) acc += __shfl_down(acc, off, 64);
        if (lane == 0) en[l] = acc;
    }
    __syncthreads();

    // masked softmax on wave 0
    if (tid < 64) {
        int mode = *mode_p;
        float e = (lane < ML_N) ? en[lane] : -1e30f;
        int pad = 0;
        if (lane < ML_N) {
            int mi = b * ML_N + lane;
            if (mode == 0)      pad = (((const int*)maskp)[mi] != 0);
            else if (mode == 1) pad = (((const float*)maskp)[mi] != 0.0f);
            else                pad = (((const unsigned char*)maskp)[mi] != 0);
        }
        float m = e;
        #pragma unroll
        for (int off = 32; off > 0; off >>= 1) m = fmaxf(m, __shfl_down(m, off, 64));
        m = __shfl(m, 0, 64);
        float x = (lane < ML_N && !pad) ? __expf(e - m) : 0.f;
        float s = x;
        #pragma unroll
        for (int off = 32; off > 0; off >>= 1) s += __shfl_down(s, off, 64);
        s = __shfl(s, 0, 64);
        nrm[lane] = x / s;
    }
    __syncthreads();

    // pass 2: contexts (two consecutive e per thread; enc re-read is cache-hot)
    float acc0 = 0.f, acc1 = 0.f;
    const float2* encb2 = (const float2*)encb;
    #pragma unroll 10
    for (int l = 0; l < ML_N; l++) {
        float2 v = encb2[l * 512 + tid];
        float w = nrm[l];
        acc0 += w * v.x;
        acc1 += w * v.y;
    }
    ((float2*)(ctx_f + (size_t)b * E_N))[tid] = make_float2(acc0, acc1);
    ((uint32_t*)(a_lstm + (size_t)b * 2048 + 1024))[tid] = packbf2(acc0, acc1);

    int wid = ts[b];
    float2 w2 = ((const float2*)(emb + (size_t)wid * E_N))[tid];
    ((uint32_t*)(a_lstm + (size_t)b * 2048))[tid] = packbf2(w2.x, w2.y);
}

// ---------------------------------------------------------------------------
// K2: bf16-MFMA GEMM with fused fp32->bf16 B conversion, 2-phase pipeline.
// out[M][N] = A[M][K](bf16) @ Bcat[N][K]^T + bias, where Bcat row n, col k is
// B1[n][k] for k<K1 else B2[n][k-K1] (fp32 inputs, converted on LDS read).
// 128x128 tile, BK=32, 256 threads. One counted-drain barrier per K-step:
// stage(t+1) issued BEFORE compute(t), vmcnt(0)+s_barrier after MFMA (T3 min).
// Grid: 1-D, XCD-bijective chunked remap, m-fastest (all mtiles blocks of one
// n-panel land adjacent on one XCD -> L2 shares the B panel).
// B fp32 LDS tile is XOR-swizzled (byte ^= (row&7)<<4) via pre-swizzled global
// source (LDS dest stays lane-linear for global_load_lds); plain layout would
// be a 16-way bank conflict on the fragment ds_read_b128.
__global__ __launch_bounds__(256) void gemm_btf(
    const bf16_t* __restrict__ A, const float* __restrict__ B1,
    const float* __restrict__ B2, const float* __restrict__ bias1,
    const float* __restrict__ bias2, float* __restrict__ out,
    int M, int N, int K, int K1, int mtiles)
{
    __shared__ __align__(16) bf16_t As[2][128 * 32];   // 16 KB
    __shared__ __align__(16) float  Bs[2][128 * 32];   // 32 KB

    int tid = threadIdx.x;
    int lane = tid & 63, wv = tid >> 6;
    int quad = lane >> 4, l16 = lane & 15;

    // XCD-bijective chunked remap (m204): consecutive logical wgs -> same XCD
    int nwg = (int)gridDim.x, bid = (int)blockIdx.x;
    int q = nwg >> 3, r = nwg & 7;
    int xcd = bid & 7, idx = bid >> 3;
    int wg = (xcd < r ? xcd * (q + 1) : r * (q + 1) + (xcd - r) * q) + idx;
    int m0 = (wg % mtiles) * 128;
    int n0 = (wg / mtiles) * 128;

    int wm = (wv >> 1) * 64, wn = (wv & 1) * 64;

    f32x4 acc[4][4];
    #pragma unroll
    for (int a = 0; a < 4; a++)
        #pragma unroll
        for (int b2 = 0; b2 < 4; b2++) { f32x4 z = {0.f, 0.f, 0.f, 0.f}; acc[a][b2] = z; }

    // staging geometry (loop-invariant)
    int rA = tid >> 2;                       // 0..63   A half-tile row
    int kA = (tid & 3) * 8;                  // bf16 elem offset
    int rB = tid >> 3;                       // 0..31   B group row
    int kB = ((tid & 7) ^ (rB & 7)) * 4;     // pre-swizzled fp32 source offset

    const bf16_t* aq0 = A + (size_t)(m0 + rA) * K + kA;

    // B row byte offsets (clamped so padded tail tiles stay in-bounds;
    // clamped rows produce garbage cols that the gn<N store guard discards)
    size_t ro0, ro1, ro2, ro3;
    {
        int r0_ = n0 + rB;      if (r0_ > N - 1) r0_ = N - 1;
        int r1_ = n0 + 32 + rB; if (r1_ > N - 1) r1_ = N - 1;
        int r2_ = n0 + 64 + rB; if (r2_ > N - 1) r2_ = N - 1;
        int r3_ = n0 + 96 + rB; if (r3_ > N - 1) r3_ = N - 1;
        ro0 = (size_t)r0_ * K1; ro1 = (size_t)r1_ * K1;
        ro2 = (size_t)r2_ * K1; ro3 = (size_t)r3_ * K1;
    }

#define STAGEF(buf, k0) do {                                              \
        const bf16_t* ap_ = aq0 + (k0);                                   \
        load_lds16(ap_,          &As[buf][0] + wv * 512);                 \
        load_lds16(ap_ + 64 * K, &As[buf][0] + 2048 + wv * 512);          \
        const float* bp_;                                                 \
        if ((k0) < K1) bp_ = B1 + (k0) + kB;                              \
        else           bp_ = B2 + ((k0) - K1) + kB;                       \
        load_lds16(bp_ + ro0, &Bs[buf][0] + wv * 256);                    \
        load_lds16(bp_ + ro1, &Bs[buf][0] + 1024 + wv * 256);             \
        load_lds16(bp_ + ro2, &Bs[buf][0] + 2048 + wv * 256);             \
        load_lds16(bp_ + ro3, &Bs[buf][0] + 3072 + wv * 256);             \
    } while (0)

    STAGEF(0, 0);
    asm volatile("s_waitcnt vmcnt(0)" ::: "memory");
    __builtin_amdgcn_s_barrier();

    int nt = K >> 5;
    int cur = 0;
    for (int t = 0; t < nt; ++t) {
        int kn = (t + 1) << 5;
        if (kn < K) STAGEF(cur ^ 1, kn);

        const bf16_t* Ac = &As[cur][0];
        const float*  Bc = &Bs[cur][0];
        bf16x8 af[4], bfr[4];
        #pragma unroll
        for (int i = 0; i < 4; i++)
            af[i] = *(const bf16x8*)(Ac + (wm + i * 16 + l16) * 32 + quad * 8);
        #pragma unroll
        for (int i = 0; i < 4; i++) {
            int rr = wn + i * 16 + l16;
            int sw = (rr & 7) << 2;
            const float* p = Bc + rr * 32;
            float4 x = *(const float4*)(p + ((quad * 8) ^ sw));
            float4 y = *(const float4*)(p + ((quad * 8 + 4) ^ sw));
            bfr[i] = cvt8(x, y);
        }
        #pragma unroll
        for (int mi = 0; mi < 4; mi++)
            #pragma unroll
            for (int ni = 0; ni < 4; ni++)
                acc[mi][ni] = __builtin_amdgcn_mfma_f32_16x16x32_bf16(
                    af[mi], bfr[ni], acc[mi][ni], 0, 0, 0);

        asm volatile("s_waitcnt vmcnt(0)" ::: "memory");
        __builtin_amdgcn_s_barrier();
        cur ^= 1;
    }
#undef STAGEF

    #pragma unroll
    for (int mi = 0; mi < 4; mi++) {
        int gm = m0 + wm + mi * 16 + quad * 4;
        #pragma unroll
        for (int ni = 0; ni < 4; ni++) {
            int gn = n0 + wn + ni * 16 + l16;
            if (gn < N) {
                float bs = bias1[gn];
                if (bias2) bs += bias2[gn];
                #pragma unroll
                for (int rw = 0; rw < 4; rw++)
                    out[(size_t)(gm + rw) * N + gn] = acc[mi][ni][rw] + bs;
            }
        }
    }
}

// ---------------------------------------------------------------------------
// K3: LSTM cell elementwise.
__global__ __launch_bounds__(256) void lstm_cell(
    const float* __restrict__ gates, const float* __restrict__ ctx,
    float* __restrict__ h_out, float* __restrict__ c_out,
    uint16_t* __restrict__ h_bf)
{
    int idx = blockIdx.x * 256 + threadIdx.x;
    int b = idx >> 10, e = idx & 1023;
    const float* g = gates + ((size_t)b << 12);
    float iv = g[e], fv = g[e + 1024], gv = g[e + 2048], ov = g[e + 3072];
    iv = 1.f / (1.f + __expf(-iv));
    fv = 1.f / (1.f + __expf(-fv));
    gv = tanhf(gv);
    ov = 1.f / (1.f + __expf(-ov));
    float c = fv * ctx[idx] + iv * gv;
    float h = ov * tanhf(c);
    c_out[idx] = c;
    h_out[idx] = h;
    h_bf[idx] = f2bf(h);
}

// ---------------------------------------------------------------------------
extern "C" void kernel_launch(void* const* d_in, const int* in_sizes, int n_in,
                              void* d_out, int out_size, void* d_ws, size_t ws_size,
                              hipStream_t stream)
{
    const int*   ts     = (const int*)d_in[0];
    const float* enc    = (const float*)d_in[1];
    const float* h0     = (const float*)d_in[2];
    const void*  mask   = d_in[4];
    const float* emb    = (const float*)d_in[6];
    const float* w_ih   = (const float*)d_in[7];
    const float* w_hh   = (const float*)d_in[8];
    const float* b_ih   = (const float*)d_in[9];
    const float* b_hh   = (const float*)d_in[10];
    const float* w_proj = (const float*)d_in[11];
    const float* b_proj = (const float*)d_in[12];
    float* out = (float*)d_out;

    // ws layout (5.25 MB total)
    char* ws = (char*)d_ws;
    size_t off = 0;
    int*      mode   = (int*)(ws + off);      off += 256;
    float*    ctx_f  = (float*)(ws + off);    off += (size_t)B_N * E_N * 4;   // 2 MB
    bf16_t*   a_lstm = (bf16_t*)(ws + off);   off += (size_t)B_N * 2048 * 2;  // 2 MB
    uint16_t* h_bf   = (uint16_t*)(ws + off); off += (size_t)B_N * E_N * 2;   // 1 MB

    float* gates = out;                                  // reuse logits region
    float* h_out = out + (size_t)B_N * V_N;
    float* c_out = h_out + (size_t)B_N * E_N;

    detect_mask_mode<<<1, 256, 0, stream>>>((const uint32_t*)mask, mode);
    attn_kernel<<<B_N, 512, 0, stream>>>(enc, h0, mask, mode, ts, emb, ctx_f, a_lstm);

    // gates = [words|ctx] @ [w_ih|w_hh]^T + b_ih + b_hh   (M=512, N=4096, K=2048)
    gemm_btf<<<128, 256, 0, stream>>>(a_lstm, w_ih, w_hh, b_ih, b_hh,
                                      gates, B_N, 4096, 2048, 1024, 4);
    lstm_cell<<<(B_N * E_N) / 256, 256, 0, stream>>>(gates, ctx_f, h_out, c_out, h_bf);
    // logits = h_new @ w_proj^T + b_proj                  (M=512, N=50000, K=1024)
    gemm_btf<<<1564, 256, 0, stream>>>((const bf16_t*)h_bf, w_proj, w_proj,
                                       b_proj, nullptr, out, B_N, V_N, 1024, 1024, 4);
}

// Round 2
// 645.301 us; speedup vs baseline: 1.0703x; 1.0494x over previous
//
#include <hip/hip_runtime.h>
#include <stdint.h>

#define B_N 512
#define E_N 1024
#define ML_N 50
#define V_N 50000
#define V_PAD 50048   // 391 * 128

typedef __bf16 bf16_t;
typedef __bf16 bf16x8 __attribute__((ext_vector_type(8)));
typedef float f32x4 __attribute__((ext_vector_type(4)));

__device__ __forceinline__ uint16_t f2bf(float f) {
    union { float f; uint32_t u; } v; v.f = f;
    return (uint16_t)((v.u + 0x7FFFu + ((v.u >> 16) & 1u)) >> 16);  // RNE
}
__device__ __forceinline__ uint32_t packbf2(float lo, float hi) {
    return (uint32_t)f2bf(lo) | ((uint32_t)f2bf(hi) << 16);
}
__device__ __forceinline__ void load_lds16(const void* g, void* l) {
    __builtin_amdgcn_global_load_lds((const __attribute__((address_space(1))) void*)g,
                                     (__attribute__((address_space(3))) void*)l, 16, 0, 0);
}

// ---------------------------------------------------------------------------
// K0: classify padded_positions dtype: 0 = int32 {0,1}, 1 = float32 {0,1.0f},
// 2 = byte. Reads first 25600 bytes (in-bounds under every interpretation).
__global__ __launch_bounds__(256) void detect_mask_mode(const uint32_t* __restrict__ mp,
                                                        int* __restrict__ mode_out) {
    __shared__ int s_int_ok, s_flt_ok;
    if (threadIdx.x == 0) { s_int_ok = 1; s_flt_ok = 1; }
    __syncthreads();
    int int_ok = 1, flt_ok = 1;
    for (int i = threadIdx.x; i < 6400; i += 256) {
        uint32_t v = mp[i];
        if (!(v == 0u || v == 1u)) int_ok = 0;
        if (!(v == 0u || v == 0x3F800000u)) flt_ok = 0;
    }
    if (!int_ok) atomicAnd(&s_int_ok, 0);
    if (!flt_ok) atomicAnd(&s_flt_ok, 0);
    __syncthreads();
    if (threadIdx.x == 0) *mode_out = s_int_ok ? 0 : (s_flt_ok ? 1 : 2);
}

// ---------------------------------------------------------------------------
// K1 fused: energies + masked softmax + contexts + embed gather.
// One block per batch row, 512 threads. Pass 1 streams enc (HBM); pass 2
// re-reads the same 205 KB slice (L2/LLC-hot).
__global__ __launch_bounds__(512) void attn_kernel(
    const float* __restrict__ enc, const float* __restrict__ h0,
    const void* __restrict__ maskp, const int* __restrict__ mode_p,
    const int* __restrict__ ts, const float* __restrict__ emb,
    float* __restrict__ ctx_f, bf16_t* __restrict__ ctx_bf,
    bf16_t* __restrict__ words_bf)
{
    __shared__ float hs[E_N];
    __shared__ float en[64];
    __shared__ float nrm[64];

    int b = blockIdx.x;
    int tid = threadIdx.x;
    int lane = tid & 63, wv = tid >> 6;   // 8 waves

    if (tid < 256)
        ((float4*)hs)[tid] = ((const float4*)(h0 + (size_t)b * E_N))[tid];
    __syncthreads();

    const float* encb = enc + (size_t)b * ML_N * E_N;

    // pass 1: energies (one row per wave, strided by 8)
    for (int l = wv; l < ML_N; l += 8) {
        const float4* row = (const float4*)(encb + l * E_N);
        float acc = 0.f;
        #pragma unroll
        for (int t = 0; t < 4; t++) {
            float4 e4 = row[lane + 64 * t];
            float4 h4 = ((const float4*)hs)[lane + 64 * t];
            acc += e4.x * h4.x + e4.y * h4.y + e4.z * h4.z + e4.w * h4.w;
        }
        #pragma unroll
        for (int off = 32; off > 0; off >>= 1) acc += __shfl_down(acc, off, 64);
        if (lane == 0) en[l] = acc;
    }
    __syncthreads();

    // masked softmax on wave 0
    if (tid < 64) {
        int mode = *mode_p;
        float e = (lane < ML_N) ? en[lane] : -1e30f;
        int pad = 0;
        if (lane < ML_N) {
            int mi = b * ML_N + lane;
            if (mode == 0)      pad = (((const int*)maskp)[mi] != 0);
            else if (mode == 1) pad = (((const float*)maskp)[mi] != 0.0f);
            else                pad = (((const unsigned char*)maskp)[mi] != 0);
        }
        float m = e;
        #pragma unroll
        for (int off = 32; off > 0; off >>= 1) m = fmaxf(m, __shfl_down(m, off, 64));
        m = __shfl(m, 0, 64);
        float x = (lane < ML_N && !pad) ? __expf(e - m) : 0.f;
        float s = x;
        #pragma unroll
        for (int off = 32; off > 0; off >>= 1) s += __shfl_down(s, off, 64);
        s = __shfl(s, 0, 64);
        nrm[lane] = x / s;
    }
    __syncthreads();

    // pass 2: contexts (two consecutive e per thread; enc re-read is cache-hot)
    float acc0 = 0.f, acc1 = 0.f;
    const float2* encb2 = (const float2*)encb;
    #pragma unroll 10
    for (int l = 0; l < ML_N; l++) {
        float2 v = encb2[l * 512 + tid];
        float w = nrm[l];
        acc0 += w * v.x;
        acc1 += w * v.y;
    }
    ((float2*)(ctx_f + (size_t)b * E_N))[tid] = make_float2(acc0, acc1);
    ((uint32_t*)(ctx_bf + (size_t)b * E_N))[tid] = packbf2(acc0, acc1);

    int wid = ts[b];
    float2 w2 = ((const float2*)(emb + (size_t)wid * E_N))[tid];
    ((uint32_t*)(words_bf + (size_t)b * E_N))[tid] = packbf2(w2.x, w2.y);
}

// ---------------------------------------------------------------------------
// K2: bf16-MFMA GEMM, m97 single-buffer structure (proven ~427 TF on this
// shape), with B converted fp32->bf16 during staging (reg-staged: global
// float4 loads -> v_cvt_pk -> ds_write_b128 into a stride-40-padded bf16
// tile). A staged via global_load_lds (bf16, linear). LDS = 8 + 10 KB.
// Compiler-managed waits only (every __syncthreads drains vmcnt/lgkmcnt) --
// no manual pipeline, no race surface. B(t+1) register loads are issued at
// the top of the compute phase so their latency hides under the MFMAs.
// Dual-pair capable: blocks [0,bpp) compute out0 = A0 @ B0^T, blocks
// [bpp,2*bpp) compute out1 = A1 @ B1^T (same M,N,K). bias optional (pair 0
// semantics: bias applied to both pairs if non-null; pass null for gates).
// Grid: XCD-bijective chunked remap, m-fastest within a pair.
__global__ __launch_bounds__(256) void gemm_rs(
    const bf16_t* __restrict__ A0, const float* __restrict__ B0,
    const bf16_t* __restrict__ A1, const float* __restrict__ B1,
    const float* __restrict__ bias, float* __restrict__ out0,
    float* __restrict__ out1, int M, int N, int K, int mtiles, int bpp)
{
    __shared__ __align__(16) bf16_t As[128 * 32];   // 8 KB, linear
    __shared__ __align__(16) bf16_t Bs[128 * 40];   // 10 KB, stride-40 pad

    int tid = threadIdx.x;
    int lane = tid & 63, wv = tid >> 6;
    int quad = lane >> 4, l16 = lane & 15;

    // XCD-bijective chunked remap (m204)
    int nwg = (int)gridDim.x, bid = (int)blockIdx.x;
    int q = nwg >> 3, r = nwg & 7;
    int xcd = bid & 7, idx = bid >> 3;
    int wg = (xcd < r ? xcd * (q + 1) : r * (q + 1) + (xcd - r) * q) + idx;

    int pair = wg / bpp;
    int rr_wg = wg - pair * bpp;
    int m0 = (rr_wg % mtiles) * 128;
    int n0 = (rr_wg / mtiles) * 128;

    const bf16_t* A = pair ? A1 : A0;
    const float*  B = pair ? B1 : B0;
    float*        out = pair ? out1 : out0;

    int wm = (wv >> 1) * 64, wn = (wv & 1) * 64;

    f32x4 acc[4][4];
    #pragma unroll
    for (int a = 0; a < 4; a++)
        #pragma unroll
        for (int b2 = 0; b2 < 4; b2++) { f32x4 z = {0.f, 0.f, 0.f, 0.f}; acc[a][b2] = z; }

    // A staging geometry: thread t covers row t>>2, 8 bf16 at col (t&3)*8.
    int rA = tid >> 2, kA = (tid & 3) * 8;
    const bf16_t* aq0 = A + (size_t)(m0 + rA) * K + kA;

    // B staging geometry: thread t covers row t>>1, 16 fp32 at col (t&1)*16.
    int rB = tid >> 1, hB = tid & 1;
    int browc = n0 + rB; if (browc > N - 1) browc = N - 1;   // tail clamp
    const float* bsrc = B + (size_t)browc * K + hB * 16;

    int nt = K >> 5;

    // prologue: B(0) into registers
    float4 c0 = ((const float4*)bsrc)[0];
    float4 c1 = ((const float4*)bsrc)[1];
    float4 c2 = ((const float4*)bsrc)[2];
    float4 c3 = ((const float4*)bsrc)[3];

    for (int t = 0; t < nt; ++t) {
        int k0 = t << 5;
        __syncthreads();                       // all reads of As/Bs done
        // stage A(t) direct to LDS
        load_lds16(aq0 + k0,          As + wv * 512);
        load_lds16(aq0 + 64 * K + k0, As + 2048 + wv * 512);
        // stage B(t): cvt regs -> bf16 LDS (stride 40)
        uint4 p0, p1;
        p0.x = packbf2(c0.x, c0.y); p0.y = packbf2(c0.z, c0.w);
        p0.z = packbf2(c1.x, c1.y); p0.w = packbf2(c1.z, c1.w);
        p1.x = packbf2(c2.x, c2.y); p1.y = packbf2(c2.z, c2.w);
        p1.z = packbf2(c3.x, c3.y); p1.w = packbf2(c3.z, c3.w);
        uint4* bsp = (uint4*)(Bs + rB * 40 + hB * 16);
        bsp[0] = p0; bsp[1] = p1;
        __syncthreads();                       // drains A-lds loads + writes

        // issue B(t+1) now; latency hides under the MFMA phase
        if (t + 1 < nt) {
            const float* bp = bsrc + k0 + 32;
            c0 = ((const float4*)bp)[0];
            c1 = ((const float4*)bp)[1];
            c2 = ((const float4*)bp)[2];
            c3 = ((const float4*)bp)[3];
        }

        bf16x8 af[4], bfr[4];
        #pragma unroll
        for (int i = 0; i < 4; i++) {
            af[i]  = *(const bf16x8*)(As + (wm + i * 16 + l16) * 32 + quad * 8);
            bfr[i] = *(const bf16x8*)(Bs + (wn + i * 16 + l16) * 40 + quad * 8);
        }
        #pragma unroll
        for (int mi = 0; mi < 4; mi++)
            #pragma unroll
            for (int ni = 0; ni < 4; ni++)
                acc[mi][ni] = __builtin_amdgcn_mfma_f32_16x16x32_bf16(
                    af[mi], bfr[ni], acc[mi][ni], 0, 0, 0);
    }

    #pragma unroll
    for (int mi = 0; mi < 4; mi++) {
        int gm = m0 + wm + mi * 16 + quad * 4;
        #pragma unroll
        for (int ni = 0; ni < 4; ni++) {
            int gn = n0 + wn + ni * 16 + l16;
            if (gn < N) {
                float bs = bias ? bias[gn] : 0.f;
                #pragma unroll
                for (int rw = 0; rw < 4; rw++)
                    out[(size_t)(gm + rw) * N + gn] = acc[mi][ni][rw] + bs;
            }
        }
    }
}

// ---------------------------------------------------------------------------
// K3: LSTM cell elementwise. gates = g0 + g1 + b_ih + b_hh (the two GEMM
// halves: words@w_ih^T and ctx@w_hh^T, biases folded here).
__global__ __launch_bounds__(256) void lstm_cell(
    const float* __restrict__ g0p, const float* __restrict__ g1p,
    const float* __restrict__ b_ih, const float* __restrict__ b_hh,
    const float* __restrict__ ctx,
    float* __restrict__ h_out, float* __restrict__ c_out,
    uint16_t* __restrict__ h_bf)
{
    int idx = blockIdx.x * 256 + threadIdx.x;
    int b = idx >> 10, e = idx & 1023;
    const float* g0 = g0p + ((size_t)b << 12);
    const float* g1 = g1p + ((size_t)b << 12);
    float iv = g0[e]        + g1[e]        + b_ih[e]        + b_hh[e];
    float fv = g0[e + 1024] + g1[e + 1024] + b_ih[e + 1024] + b_hh[e + 1024];
    float gv = g0[e + 2048] + g1[e + 2048] + b_ih[e + 2048] + b_hh[e + 2048];
    float ov = g0[e + 3072] + g1[e + 3072] + b_ih[e + 3072] + b_hh[e + 3072];
    iv = 1.f / (1.f + __expf(-iv));
    fv = 1.f / (1.f + __expf(-fv));
    gv = tanhf(gv);
    ov = 1.f / (1.f + __expf(-ov));
    float c = fv * ctx[idx] + iv * gv;
    float h = ov * tanhf(c);
    c_out[idx] = c;
    h_out[idx] = h;
    h_bf[idx] = f2bf(h);
}

// ---------------------------------------------------------------------------
extern "C" void kernel_launch(void* const* d_in, const int* in_sizes, int n_in,
                              void* d_out, int out_size, void* d_ws, size_t ws_size,
                              hipStream_t stream)
{
    const int*   ts     = (const int*)d_in[0];
    const float* enc    = (const float*)d_in[1];
    const float* h0     = (const float*)d_in[2];
    const void*  mask   = d_in[4];
    const float* emb    = (const float*)d_in[6];
    const float* w_ih   = (const float*)d_in[7];
    const float* w_hh   = (const float*)d_in[8];
    const float* b_ih   = (const float*)d_in[9];
    const float* b_hh   = (const float*)d_in[10];
    const float* w_proj = (const float*)d_in[11];
    const float* b_proj = (const float*)d_in[12];
    float* out = (float*)d_out;

    // ws layout (~21.3 MB total; harness grants >= 123 MB, verified round 0)
    char* ws = (char*)d_ws;
    size_t off = 0;
    int*      mode     = (int*)(ws + off);      off += 256;
    float*    ctx_f    = (float*)(ws + off);    off += (size_t)B_N * E_N * 4;    // 2 MB
    bf16_t*   ctx_bf   = (bf16_t*)(ws + off);   off += (size_t)B_N * E_N * 2;    // 1 MB
    bf16_t*   words_bf = (bf16_t*)(ws + off);   off += (size_t)B_N * E_N * 2;    // 1 MB
    uint16_t* h_bf     = (uint16_t*)(ws + off); off += (size_t)B_N * E_N * 2;    // 1 MB
    float*    gates0   = (float*)(ws + off);    off += (size_t)B_N * 4096 * 4;   // 8 MB
    float*    gates1   = (float*)(ws + off);    off += (size_t)B_N * 4096 * 4;   // 8 MB

    float* h_out = out + (size_t)B_N * V_N;
    float* c_out = h_out + (size_t)B_N * E_N;

    detect_mask_mode<<<1, 256, 0, stream>>>((const uint32_t*)mask, mode);
    attn_kernel<<<B_N, 512, 0, stream>>>(enc, h0, mask, mode, ts, emb,
                                         ctx_f, ctx_bf, words_bf);

    // gates halves: g0 = words @ w_ih^T, g1 = ctx @ w_hh^T
    // (M=512, N=4096, K=1024 each; 2 pairs x 128 blocks = full-GPU grid)
    gemm_rs<<<256, 256, 0, stream>>>(words_bf, w_ih, ctx_bf, w_hh, nullptr,
                                     gates0, gates1, B_N, 4096, 1024, 4, 128);

    lstm_cell<<<(B_N * E_N) / 256, 256, 0, stream>>>(gates0, gates1, b_ih, b_hh,
                                                     ctx_f, h_out, c_out, h_bf);

    // logits = h_new @ w_proj^T + b_proj   (M=512, N=50000, K=1024)
    gemm_rs<<<1564, 256, 0, stream>>>((const bf16_t*)h_bf, w_proj,
                                      (const bf16_t*)h_bf, w_proj, b_proj,
                                      out, out, B_N, V_N, 1024, 4, 1564);
}